// Round 6
// baseline (1767.764 us; speedup 1.0000x reference)
//
#include <hip/hip_runtime.h>

#define DEV __device__ __forceinline__

typedef __bf16 bf16x8 __attribute__((ext_vector_type(8)));
typedef float  f32x4  __attribute__((ext_vector_type(4)));

DEV float b2f(unsigned short u) {
    unsigned int t = ((unsigned int)u) << 16;
    return __uint_as_float(t);
}
DEV unsigned short f2b(float f) {
    unsigned int u = __float_as_uint(f);
    unsigned int r = (u + 0x7FFFu + ((u >> 16) & 1u)) >> 16;
    return (unsigned short)r;
}

// dest window-row -> source/dest token index (roll by SS=3, window 7x7, 56x56, 64 win/batch)
DEV size_t win_to_tok(int row) {
    int w = row / 49, t = row - w * 49;
    int b  = w >> 6, widx = w & 63;
    int wi = widx >> 3, wj = widx & 7;
    int ti = t / 7, tj = t - ti * 7;
    int hh = wi * 7 + ti + 3; if (hh >= 56) hh -= 56;
    int ww = wj * 7 + tj + 3; if (ww >= 56) ww -= 56;
    return (size_t)b * 3136 + (size_t)hh * 56 + ww;
}

// ---------------- weight prep: fp32 [K][N] -> bf16 [N][K] ----------------
__global__ void wprep(const float* __restrict__ src, unsigned short* __restrict__ dst,
                      int K, int N) {
    int idx = blockIdx.x * 256 + threadIdx.x;
    if (idx >= K * N) return;
    int k = idx / N, n = idx - k * N;
    dst[(size_t)n * K + k] = f2b(src[idx]);
}

// ---------------- LayerNorm (+optional shifted-window gather), fp32 -> bf16 ----------------
template <int REMAP>
__global__ __launch_bounds__(256) void ln_kernel(const float* __restrict__ x,
                                                 const float* __restrict__ g,
                                                 const float* __restrict__ b,
                                                 unsigned short* __restrict__ out,
                                                 int rows) {
    int r = blockIdx.x * 4 + (threadIdx.x >> 6);
    int lane = threadIdx.x & 63;
    if (r >= rows) return;
    size_t src = REMAP ? win_to_tok(r) : (size_t)r;
    const float* xp = x + src * 384;
    float v[6];
    float s = 0.f;
#pragma unroll
    for (int i = 0; i < 6; ++i) { v[i] = xp[i * 64 + lane]; s += v[i]; }
#pragma unroll
    for (int off = 32; off; off >>= 1) s += __shfl_xor(s, off, 64);
    float mu = s * (1.f / 384.f);
    float q = 0.f;
#pragma unroll
    for (int i = 0; i < 6; ++i) { float d = v[i] - mu; q += d * d; }
#pragma unroll
    for (int off = 32; off; off >>= 1) q += __shfl_xor(q, off, 64);
    float inv = rsqrtf(q * (1.f / 384.f) + 1e-5f);
    unsigned short* op = out + (size_t)r * 384;
#pragma unroll
    for (int i = 0; i < 6; ++i) {
        int c = i * 64 + lane;
        op[c] = f2b((v[i] - mu) * inv * g[c] + b[c]);
    }
}

// ---------------- GEMM: C[M][N] = A[M][K] (bf16, row-major) x Bt[N][K] (bf16) ----------------
// LDS-free: MFMA fragments loaded directly global->VGPR (B is L2-resident, A streamed;
// no barriers, no staging lockstep -> compiler pipelines loads across MFMAs).
// Fragment layout: lane reads 8 bf16 at row (lane&15), k-chunk (lane>>4)*8 — identical
// to the verified LDS fragment layout, addresses fully coalesced (4 lanes per 64B line).
// MODE 0: out bf16 = C                               (QKV)
// MODE 1: h[tok] = x[tok] + C + bias  (un-window+un-roll remap, fp32 out)   (proj)
// MODE 2: out bf16 = gelu(C + bias)   (tanh-form)    (FFN1)
// MODE 3: outf = resid + C + bias  (resid may alias outf)                   (FFN2)
template <int MODE>
__global__ __launch_bounds__(256) void gemm_kernel(const unsigned short* __restrict__ A,
                                                   const unsigned short* __restrict__ Bt,
                                                   int M, int N, int K,
                                                   const float* __restrict__ bias,
                                                   const float* __restrict__ resid,
                                                   unsigned short* __restrict__ outb,
                                                   float* __restrict__ outf) {
    const int tid = threadIdx.x;
    const int wid = tid >> 6, lane = tid & 63;
    const int ntile = N >> 7;

    // XCD-aware block swizzle: contiguous chunk of (mt,nt) space per XCD (grid % 8 == 0);
    // nt fastest within a chunk -> the N-tile blocks sharing an A-panel land on one XCD's L2.
    int bid = blockIdx.x;
    int nwg = gridDim.x;
    int swb = ((nwg & 7) == 0) ? ((bid & 7) * (nwg >> 3) + (bid >> 3)) : bid;
    const int mt = swb / ntile, nt = swb - mt * ntile;
    const int wr = wid >> 1, wc = wid & 1;

    f32x4 acc[4][4] = {};

    const int rsel = lane & 15;          // row within 16-row fragment
    const int ksel = (lane >> 4) << 3;   // 8-element k-chunk

    const unsigned short* ap[4];
    const unsigned short* bp[4];
#pragma unroll
    for (int m = 0; m < 4; ++m)
        ap[m] = A + (size_t)(mt * 128 + wr * 64 + m * 16 + rsel) * K + ksel;
#pragma unroll
    for (int n = 0; n < 4; ++n)
        bp[n] = Bt + (size_t)(nt * 128 + wc * 64 + n * 16 + rsel) * K + ksel;

    const int nk = K >> 5;
#pragma unroll 4
    for (int t = 0; t < nk; ++t) {
        const int k0 = t << 5;
        bf16x8 a[4], b[4];
#pragma unroll
        for (int m = 0; m < 4; ++m) a[m] = *(const bf16x8*)(ap[m] + k0);
#pragma unroll
        for (int n = 0; n < 4; ++n) b[n] = *(const bf16x8*)(bp[n] + k0);
#pragma unroll
        for (int m = 0; m < 4; ++m)
#pragma unroll
            for (int n = 0; n < 4; ++n)
                acc[m][n] = __builtin_amdgcn_mfma_f32_16x16x32_bf16(a[m], b[n], acc[m][n], 0, 0, 0);
    }

    const int row0 = mt * 128 + wr * 64;
    const int col0 = nt * 128 + wc * 64;
#pragma unroll
    for (int m = 0; m < 4; ++m) {
#pragma unroll
        for (int r = 0; r < 4; ++r) {
            int row = row0 + m * 16 + ((lane >> 4) << 2) + r;
            size_t tok = 0;
            if constexpr (MODE == 1) tok = win_to_tok(row);
#pragma unroll
            for (int n = 0; n < 4; ++n) {
                int col = col0 + n * 16 + (lane & 15);
                float v = acc[m][n][r];
                if constexpr (MODE == 0) {
                    outb[(size_t)row * N + col] = f2b(v);
                } else if constexpr (MODE == 1) {
                    size_t o = tok * 384 + col;
                    outf[o] = resid[o] + v + bias[col];
                } else if constexpr (MODE == 2) {
                    // tanh-form GELU, overflow-safe (err ~3e-4, << bf16 rounding of F)
                    float t2 = v + bias[col];
                    float y  = 0.7978845608028654f * (t2 + 0.044715f * t2 * t2 * t2);
                    float u  = __expf(-2.0f * fabsf(y));
                    float th = (1.f - u) / (1.f + u);
                    outb[(size_t)row * N + col] = f2b(0.5f * t2 * (1.f + copysignf(th, t2)));
                } else {
                    size_t o = (size_t)row * N + col;
                    outf[o] = resid[o] + v + bias[col];
                }
            }
        }
    }
}

// ---------------- attention: one wave per (window, head) ----------------
__global__ __launch_bounds__(64) void attn_kernel(const unsigned short* __restrict__ QKV,
                                                  const int* __restrict__ rel_idx,
                                                  const float* __restrict__ rpb,
                                                  unsigned short* __restrict__ O) {
    __shared__ float Ks[49 * 32];
    __shared__ float Vs[49 * 32];
    int w = blockIdx.x / 12, hd = blockIdx.x - w * 12;
    int lane = threadIdx.x;
    const size_t base = (size_t)w * 49 * 1152;

    for (int i = lane; i < 1568; i += 64) {
        int m = i >> 5, d = i & 31;
        Ks[i] = b2f(QKV[base + (size_t)m * 1152 + 384 + hd * 32 + d]);
        Vs[i] = b2f(QKV[base + (size_t)m * 1152 + 768 + hd * 32 + d]);
    }
    __syncthreads();

    int n = lane < 49 ? lane : 48;
    float q[32];
#pragma unroll
    for (int d = 0; d < 32; ++d)
        q[d] = b2f(QKV[base + (size_t)n * 1152 + hd * 32 + d]) * 0.17677669529663687f;

    int widx = w & 63;
    int wi = widx >> 3, wj = widx & 7;
    auto regionOf = [](int c) { return c < 49 ? 0 : (c < 53 ? 1 : 2); };
    int ti = n / 7, tj = n - (n / 7) * 7;
    int labq = regionOf(wi * 7 + ti) * 3 + regionOf(wj * 7 + tj);

    float sc[49];
    float mx = -1e30f;
#pragma unroll
    for (int m = 0; m < 49; ++m) {
        float s = 0.f;
#pragma unroll
        for (int d = 0; d < 32; ++d) s += q[d] * Ks[m * 32 + d];
        s += rpb[rel_idx[n * 49 + m] * 12 + hd];
        int mi = m / 7, mj = m - (m / 7) * 7;
        int labk = regionOf(wi * 7 + mi) * 3 + regionOf(wj * 7 + mj);
        if (labk != labq) s -= 100.f;
        sc[m] = s;
        mx = fmaxf(mx, s);
    }
    float sum = 0.f;
#pragma unroll
    for (int m = 0; m < 49; ++m) { float e = __expf(sc[m] - mx); sc[m] = e; sum += e; }
    float rinv = 1.f / sum;
    float o[32] = {};
#pragma unroll
    for (int m = 0; m < 49; ++m) {
        float p = sc[m] * rinv;
#pragma unroll
        for (int d = 0; d < 32; ++d) o[d] += p * Vs[m * 32 + d];
    }
    if (lane < 49) {
        unsigned short* op = O + ((size_t)w * 49 + n) * 384 + hd * 32;
#pragma unroll
        for (int d = 0; d < 32; ++d) op[d] = f2b(o[d]);
    }
}

extern "C" void kernel_launch(void* const* d_in, const int* in_sizes, int n_in,
                              void* d_out, int out_size, void* d_ws, size_t ws_size,
                              hipStream_t stream) {
    const float* x     = (const float*)d_in[0];
    const int*   rel   = (const int*)  d_in[3];
    const float* rpb   = (const float*)d_in[4];
    const float* qkvw  = (const float*)d_in[5];
    const float* projw = (const float*)d_in[6];
    const float* projb = (const float*)d_in[7];
    const float* n1g   = (const float*)d_in[8];
    const float* n1b   = (const float*)d_in[9];
    const float* n2g   = (const float*)d_in[10];
    const float* n2b   = (const float*)d_in[11];
    const float* w1    = (const float*)d_in[12];
    const float* b1    = (const float*)d_in[13];
    const float* w2    = (const float*)d_in[14];
    const float* b2    = (const float*)d_in[15];
    float* out = (float*)d_out;

    const int T = in_sizes[0] / 384;   // 100352

    // ---- workspace layout (Hh lives in d_out) ----
    char* ws = (char*)d_ws;
    size_t off = 0;
    auto alloc = [&](size_t bytes) {
        char* p = ws + off;
        off += (bytes + 255) & ~(size_t)255;
        return p;
    };
    unsigned short* WqT = (unsigned short*)alloc((size_t)1152 * 384 * 2);
    unsigned short* WpT = (unsigned short*)alloc((size_t)384 * 384 * 2);
    unsigned short* W1T = (unsigned short*)alloc((size_t)1536 * 384 * 2);
    unsigned short* W2T = (unsigned short*)alloc((size_t)384 * 1536 * 2);
    unsigned short* slotA = (unsigned short*)alloc((size_t)T * 384 * 2);   // X1 -> O -> X2
    unsigned short* slotB = (unsigned short*)alloc((size_t)T * 1536 * 2);  // QKV -> F

    unsigned short* X1  = slotA;
    unsigned short* O   = slotA;
    unsigned short* X2  = slotA;
    unsigned short* QKV = slotB;
    unsigned short* F   = slotB;
    float*          Hh  = out;

    wprep<<<dim3((1152 * 384 + 255) / 256), 256, 0, stream>>>(qkvw, WqT, 384, 1152);
    wprep<<<dim3((384 * 384 + 255) / 256),  256, 0, stream>>>(projw, WpT, 384, 384);
    wprep<<<dim3((384 * 1536 + 255) / 256), 256, 0, stream>>>(w1, W1T, 384, 1536);
    wprep<<<dim3((1536 * 384 + 255) / 256), 256, 0, stream>>>(w2, W2T, 1536, 384);

    // LN1 + shifted-window gather -> X1 (bf16, window-token order)
    ln_kernel<1><<<dim3(T / 4), 256, 0, stream>>>(x, n1g, n1b, X1, T);
    // QKV projection
    gemm_kernel<0><<<dim3((T / 128) * (1152 / 128)), 256, 0, stream>>>(
        X1, WqT, T, 1152, 384, nullptr, nullptr, QKV, nullptr);
    // windowed attention (reads QKV/slotB, writes O/slotA)
    attn_kernel<<<dim3((T / 49) * 12), 64, 0, stream>>>(QKV, rel, rpb, O);
    // proj + bias + un-window/un-roll + residual -> Hh (= d_out, fp32)
    gemm_kernel<1><<<dim3((T / 128) * (384 / 128)), 256, 0, stream>>>(
        O, WpT, T, 384, 384, projb, x, nullptr, Hh);
    // LN2 -> X2 (bf16, overwrites slotA)
    ln_kernel<0><<<dim3(T / 4), 256, 0, stream>>>(Hh, n2g, n2b, X2, T);
    // FFN1 + bias + GELU -> F (bf16, overwrites slotB)
    gemm_kernel<2><<<dim3((T / 128) * (1536 / 128)), 256, 0, stream>>>(
        X2, W1T, T, 1536, 384, b1, nullptr, F, nullptr);
    // FFN2 + bias + residual -> out (fp32, in-place RMW on d_out)
    gemm_kernel<3><<<dim3((T / 128) * (384 / 128)), 256, 0, stream>>>(
        F, W2T, T, 384, 1536, b2, Hh, nullptr, out);
}

// Round 7
// 1049.582 us; speedup vs baseline: 1.6843x; 1.6843x over previous
//
#include <hip/hip_runtime.h>

#define DEV __device__ __forceinline__

typedef __bf16 bf16x8 __attribute__((ext_vector_type(8)));
typedef float  f32x4  __attribute__((ext_vector_type(4)));

DEV float b2f(unsigned short u) {
    unsigned int t = ((unsigned int)u) << 16;
    return __uint_as_float(t);
}
DEV unsigned short f2b(float f) {
    unsigned int u = __float_as_uint(f);
    unsigned int r = (u + 0x7FFFu + ((u >> 16) & 1u)) >> 16;
    return (unsigned short)r;
}

DEV void gload_lds16(const unsigned short* g, unsigned short* l) {
    __builtin_amdgcn_global_load_lds(
        (const __attribute__((address_space(1))) void*)(const void*)g,
        (__attribute__((address_space(3))) void*)(void*)l, 16, 0, 0);
}

// dest window-row -> source/dest token index (roll by SS=3, window 7x7, 56x56, 64 win/batch)
DEV size_t win_to_tok(int row) {
    int w = row / 49, t = row - w * 49;
    int b  = w >> 6, widx = w & 63;
    int wi = widx >> 3, wj = widx & 7;
    int ti = t / 7, tj = t - ti * 7;
    int hh = wi * 7 + ti + 3; if (hh >= 56) hh -= 56;
    int ww = wj * 7 + tj + 3; if (ww >= 56) ww -= 56;
    return (size_t)b * 3136 + (size_t)hh * 56 + ww;
}

// ---------------- weight prep: fp32 [K][N] -> bf16 [N][K] ----------------
__global__ void wprep(const float* __restrict__ src, unsigned short* __restrict__ dst,
                      int K, int N) {
    int idx = blockIdx.x * 256 + threadIdx.x;
    if (idx >= K * N) return;
    int k = idx / N, n = idx - k * N;
    dst[(size_t)n * K + k] = f2b(src[idx]);
}

// ---------------- LayerNorm (+optional shifted-window gather), fp32 -> bf16 ----------------
template <int REMAP>
__global__ __launch_bounds__(256) void ln_kernel(const float* __restrict__ x,
                                                 const float* __restrict__ g,
                                                 const float* __restrict__ b,
                                                 unsigned short* __restrict__ out,
                                                 int rows) {
    int r = blockIdx.x * 4 + (threadIdx.x >> 6);
    int lane = threadIdx.x & 63;
    if (r >= rows) return;
    size_t src = REMAP ? win_to_tok(r) : (size_t)r;
    const float* xp = x + src * 384;
    float v[6];
    float s = 0.f;
#pragma unroll
    for (int i = 0; i < 6; ++i) { v[i] = xp[i * 64 + lane]; s += v[i]; }
#pragma unroll
    for (int off = 32; off; off >>= 1) s += __shfl_xor(s, off, 64);
    float mu = s * (1.f / 384.f);
    float q = 0.f;
#pragma unroll
    for (int i = 0; i < 6; ++i) { float d = v[i] - mu; q += d * d; }
#pragma unroll
    for (int off = 32; off; off >>= 1) q += __shfl_xor(q, off, 64);
    float inv = rsqrtf(q * (1.f / 384.f) + 1e-5f);
    unsigned short* op = out + (size_t)r * 384;
#pragma unroll
    for (int i = 0; i < 6; ++i) {
        int c = i * 64 + lane;
        op[c] = f2b((v[i] - mu) * inv * g[c] + b[c]);
    }
}

// ---------------- GEMM: C[M][N] = A[M][K] (bf16, row-major) x Bt[N][K] (bf16) ----------------
// (DEPTH+1)-buffer LDS ring, prefetch depth DEPTH with counted vmcnt, LDS XOR swizzle
// (pre-swizzled global source since global_load_lds writes linearly), XCD block swizzle.
// DEPTH=1 (32 KB LDS) for short-K / L2-resident inputs (residency/TLP wins);
// DEPTH=3 (64 KB LDS) for long-K HBM-streamed A (pipeline depth wins).
// MINW: __launch_bounds__ min-waves-per-EU (4 caps regs at 128 -> 4 waves/SIMD).
// MODE 0: out bf16 = C                               (QKV)
// MODE 1: h[tok] = x[tok] + C + bias  (un-window+un-roll remap, fp32 out)   (proj)
// MODE 2: out bf16 = gelu(C + bias)   (tanh-form)    (FFN1)
// MODE 3: outf = resid + C + bias  (resid may alias outf)                   (FFN2)
template <int MODE, int DEPTH, int MINW>
__global__ __launch_bounds__(256, MINW) void gemm_kernel(const unsigned short* __restrict__ A,
                                                         const unsigned short* __restrict__ Bt,
                                                         int M, int N, int K,
                                                         const float* __restrict__ bias,
                                                         const float* __restrict__ resid,
                                                         unsigned short* __restrict__ outb,
                                                         float* __restrict__ outf) {
    constexpr int NBUF = DEPTH + 1;
    __shared__ unsigned short As[NBUF][128 * 32];
    __shared__ unsigned short Bs[NBUF][128 * 32];
    const int tid = threadIdx.x;
    const int wid = tid >> 6, lane = tid & 63;
    const int ntile = N >> 7;

    // XCD-aware block swizzle: contiguous chunk of (mt,nt) space per XCD (grid % 8 == 0)
    int bid = blockIdx.x;
    int nwg = gridDim.x;
    int swb = ((nwg & 7) == 0) ? ((bid & 7) * (nwg >> 3) + (bid >> 3)) : bid;
    const int mt = swb / ntile, nt = swb - mt * ntile;
    const int wr = wid >> 1, wc = wid & 1;

    f32x4 acc[4][4] = {};

    // staging: lane l writes LDS linearly (row = base16 + l>>2, chunk p = l&3);
    // physical slot (row,p) holds logical chunk p ^ ((row>>1)&3), so fetch
    // global chunk (l&3) ^ ((l>>3)&3).
    const int rA   = lane >> 2;
    const int kofs = (((lane & 3) ^ ((lane >> 3) & 3)) << 3);
    const unsigned short* Abase = A  + (size_t)(mt * 128) * K;
    const unsigned short* Bbase = Bt + (size_t)(nt * 128) * K;

    auto stage = [&](int buf, int k0) {
#pragma unroll
        for (int j = 0; j < 2; ++j) {
            int c = wid * 2 + j;
            gload_lds16(Abase + (size_t)(c * 16 + rA) * K + k0 + kofs, &As[buf][c * 512]);
            gload_lds16(Bbase + (size_t)(c * 16 + rA) * K + k0 + kofs, &Bs[buf][c * 512]);
        }
    };

    // fragment-read swizzle: logical chunk cb=lane>>4 of row r lives at slot cb ^ ((r>>1)&3).
    const int sr  = ((lane & 15) >> 1) & 3;
    const int cbA = (((lane >> 4) ^ sr) << 3);
    const int rowA = wr * 64 + (lane & 15);
    const int rowB = wc * 64 + (lane & 15);

    const int nk = K >> 5;
    // prologue: prefetch up to DEPTH tiles
    stage(0, 0);
    if (DEPTH >= 2 && nk > 1) stage(1, 32);
    if (DEPTH >= 3 && nk > 2) stage(2, 64);

    for (int t = 0; t < nk; ++t) {
        const int cur = t % NBUF;
        // issue prefetch for t+DEPTH, then wait for tile t's own loads, barrier
        if (t + DEPTH < nk) {
            stage((t + DEPTH) % NBUF, (t + DEPTH) << 5);
            if constexpr (DEPTH == 1) {
                asm volatile("s_waitcnt vmcnt(4)" ::: "memory");
            } else {
                asm volatile("s_waitcnt vmcnt(12)" ::: "memory");
            }
        } else if (DEPTH >= 3 && t + 2 < nk) {
            asm volatile("s_waitcnt vmcnt(8)" ::: "memory");
        } else if (t + 1 < nk) {
            asm volatile("s_waitcnt vmcnt(4)" ::: "memory");
        } else {
            asm volatile("s_waitcnt vmcnt(0)" ::: "memory");
        }
        __builtin_amdgcn_s_barrier();   // tile t resident for every wave

        bf16x8 a[4], b[4];
#pragma unroll
        for (int m = 0; m < 4; ++m)
            a[m] = *(const bf16x8*)&As[cur][(rowA + m * 16) * 32 + cbA];
#pragma unroll
        for (int n = 0; n < 4; ++n)
            b[n] = *(const bf16x8*)&Bs[cur][(rowB + n * 16) * 32 + cbA];
#pragma unroll
        for (int m = 0; m < 4; ++m)
#pragma unroll
            for (int n = 0; n < 4; ++n)
                acc[m][n] = __builtin_amdgcn_mfma_f32_16x16x32_bf16(a[m], b[n], acc[m][n], 0, 0, 0);

        asm volatile("s_waitcnt lgkmcnt(0)" ::: "memory");  // LDS reads of buf cur retired
        __builtin_amdgcn_s_barrier();                       // buf cur may be overwritten
    }

    const int row0 = mt * 128 + wr * 64;
    const int col0 = nt * 128 + wc * 64;
#pragma unroll
    for (int m = 0; m < 4; ++m) {
#pragma unroll
        for (int r = 0; r < 4; ++r) {
            int row = row0 + m * 16 + ((lane >> 4) << 2) + r;
            size_t tok = 0;
            if constexpr (MODE == 1) tok = win_to_tok(row);
#pragma unroll
            for (int n = 0; n < 4; ++n) {
                int col = col0 + n * 16 + (lane & 15);
                float v = acc[m][n][r];
                if constexpr (MODE == 0) {
                    outb[(size_t)row * N + col] = f2b(v);
                } else if constexpr (MODE == 1) {
                    size_t o = tok * 384 + col;
                    outf[o] = resid[o] + v + bias[col];
                } else if constexpr (MODE == 2) {
                    // tanh-form GELU, overflow-safe (err ~3e-4, << bf16 rounding of F)
                    float t2 = v + bias[col];
                    float y  = 0.7978845608028654f * (t2 + 0.044715f * t2 * t2 * t2);
                    float u  = __expf(-2.0f * fabsf(y));
                    float th = (1.f - u) / (1.f + u);
                    outb[(size_t)row * N + col] = f2b(0.5f * t2 * (1.f + copysignf(th, t2)));
                } else {
                    size_t o = (size_t)row * N + col;
                    outf[o] = resid[o] + v + bias[col];
                }
            }
        }
    }
}

// ---------------- attention: one wave per (window, head) ----------------
__global__ __launch_bounds__(64) void attn_kernel(const unsigned short* __restrict__ QKV,
                                                  const int* __restrict__ rel_idx,
                                                  const float* __restrict__ rpb,
                                                  unsigned short* __restrict__ O) {
    __shared__ float Ks[49 * 32];
    __shared__ float Vs[49 * 32];
    int w = blockIdx.x / 12, hd = blockIdx.x - w * 12;
    int lane = threadIdx.x;
    const size_t base = (size_t)w * 49 * 1152;

    for (int i = lane; i < 1568; i += 64) {
        int m = i >> 5, d = i & 31;
        Ks[i] = b2f(QKV[base + (size_t)m * 1152 + 384 + hd * 32 + d]);
        Vs[i] = b2f(QKV[base + (size_t)m * 1152 + 768 + hd * 32 + d]);
    }
    __syncthreads();

    int n = lane < 49 ? lane : 48;
    float q[32];
#pragma unroll
    for (int d = 0; d < 32; ++d)
        q[d] = b2f(QKV[base + (size_t)n * 1152 + hd * 32 + d]) * 0.17677669529663687f;

    int widx = w & 63;
    int wi = widx >> 3, wj = widx & 7;
    auto regionOf = [](int c) { return c < 49 ? 0 : (c < 53 ? 1 : 2); };
    int ti = n / 7, tj = n - (n / 7) * 7;
    int labq = regionOf(wi * 7 + ti) * 3 + regionOf(wj * 7 + tj);

    float sc[49];
    float mx = -1e30f;
#pragma unroll
    for (int m = 0; m < 49; ++m) {
        float s = 0.f;
#pragma unroll
        for (int d = 0; d < 32; ++d) s += q[d] * Ks[m * 32 + d];
        s += rpb[rel_idx[n * 49 + m] * 12 + hd];
        int mi = m / 7, mj = m - (m / 7) * 7;
        int labk = regionOf(wi * 7 + mi) * 3 + regionOf(wj * 7 + mj);
        if (labk != labq) s -= 100.f;
        sc[m] = s;
        mx = fmaxf(mx, s);
    }
    float sum = 0.f;
#pragma unroll
    for (int m = 0; m < 49; ++m) { float e = __expf(sc[m] - mx); sc[m] = e; sum += e; }
    float rinv = 1.f / sum;
    float o[32] = {};
#pragma unroll
    for (int m = 0; m < 49; ++m) {
        float p = sc[m] * rinv;
#pragma unroll
        for (int d = 0; d < 32; ++d) o[d] += p * Vs[m * 32 + d];
    }
    if (lane < 49) {
        unsigned short* op = O + ((size_t)w * 49 + n) * 384 + hd * 32;
#pragma unroll
        for (int d = 0; d < 32; ++d) op[d] = f2b(o[d]);
    }
}

extern "C" void kernel_launch(void* const* d_in, const int* in_sizes, int n_in,
                              void* d_out, int out_size, void* d_ws, size_t ws_size,
                              hipStream_t stream) {
    const float* x     = (const float*)d_in[0];
    const int*   rel   = (const int*)  d_in[3];
    const float* rpb   = (const float*)d_in[4];
    const float* qkvw  = (const float*)d_in[5];
    const float* projw = (const float*)d_in[6];
    const float* projb = (const float*)d_in[7];
    const float* n1g   = (const float*)d_in[8];
    const float* n1b   = (const float*)d_in[9];
    const float* n2g   = (const float*)d_in[10];
    const float* n2b   = (const float*)d_in[11];
    const float* w1    = (const float*)d_in[12];
    const float* b1    = (const float*)d_in[13];
    const float* w2    = (const float*)d_in[14];
    const float* b2    = (const float*)d_in[15];
    float* out = (float*)d_out;

    const int T = in_sizes[0] / 384;   // 100352

    // ---- workspace layout (Hh lives in d_out) ----
    char* ws = (char*)d_ws;
    size_t off = 0;
    auto alloc = [&](size_t bytes) {
        char* p = ws + off;
        off += (bytes + 255) & ~(size_t)255;
        return p;
    };
    unsigned short* WqT = (unsigned short*)alloc((size_t)1152 * 384 * 2);
    unsigned short* WpT = (unsigned short*)alloc((size_t)384 * 384 * 2);
    unsigned short* W1T = (unsigned short*)alloc((size_t)1536 * 384 * 2);
    unsigned short* W2T = (unsigned short*)alloc((size_t)384 * 1536 * 2);
    unsigned short* slotA = (unsigned short*)alloc((size_t)T * 384 * 2);   // X1 -> O -> X2
    unsigned short* slotB = (unsigned short*)alloc((size_t)T * 1536 * 2);  // QKV -> F

    unsigned short* X1  = slotA;
    unsigned short* O   = slotA;
    unsigned short* X2  = slotA;
    unsigned short* QKV = slotB;
    unsigned short* F   = slotB;
    float*          Hh  = out;

    wprep<<<dim3((1152 * 384 + 255) / 256), 256, 0, stream>>>(qkvw, WqT, 384, 1152);
    wprep<<<dim3((384 * 384 + 255) / 256),  256, 0, stream>>>(projw, WpT, 384, 384);
    wprep<<<dim3((384 * 1536 + 255) / 256), 256, 0, stream>>>(w1, W1T, 384, 1536);
    wprep<<<dim3((1536 * 384 + 255) / 256), 256, 0, stream>>>(w2, W2T, 1536, 384);

    // LN1 + shifted-window gather -> X1 (bf16, window-token order)
    ln_kernel<1><<<dim3(T / 4), 256, 0, stream>>>(x, n1g, n1b, X1, T);
    // QKV projection (K=384: depth-1, reg-capped for occupancy)
    gemm_kernel<0, 1, 4><<<dim3((T / 128) * (1152 / 128)), 256, 0, stream>>>(
        X1, WqT, T, 1152, 384, nullptr, nullptr, QKV, nullptr);
    // windowed attention (reads QKV/slotB, writes O/slotA)
    attn_kernel<<<dim3((T / 49) * 12), 64, 0, stream>>>(QKV, rel, rpb, O);
    // proj + bias + un-window/un-roll + residual -> Hh (= d_out, fp32)
    gemm_kernel<1, 1, 4><<<dim3((T / 128) * (384 / 128)), 256, 0, stream>>>(
        O, WpT, T, 384, 384, projb, x, nullptr, Hh);
    // LN2 -> X2 (bf16, overwrites slotA)
    ln_kernel<0><<<dim3(T / 4), 256, 0, stream>>>(Hh, n2g, n2b, X2, T);
    // FFN1 + bias + GELU -> F (bf16, overwrites slotB)
    gemm_kernel<2, 1, 4><<<dim3((T / 128) * (1536 / 128)), 256, 0, stream>>>(
        X2, W1T, T, 1536, 384, b1, nullptr, F, nullptr);
    // FFN2 + bias + residual -> out (fp32, in-place RMW on d_out; K=1536: depth-3)
    gemm_kernel<3, 3, 2><<<dim3((T / 128) * (384 / 128)), 256, 0, stream>>>(
        F, W2T, T, 384, 1536, b2, Hh, nullptr, out);
}